// Round 8
// baseline (528.082 us; speedup 1.0000x reference)
//
#include <hip/hip_runtime.h>
#include <stdint.h>

#define BB 2
#define HH 16
#define LL 2048
#define DD 1024
#define HDD 64
#define NC 512

typedef __bf16 bf16x8 __attribute__((ext_vector_type(8)));
typedef float f32x4 __attribute__((ext_vector_type(4)));
typedef unsigned short u16x8 __attribute__((ext_vector_type(8)));
typedef unsigned short u16x4 __attribute__((ext_vector_type(4)));

__device__ __forceinline__ unsigned short f2bf(float f) {
  union { float f; unsigned u; } v; v.f = f;
  unsigned u = v.u;
  u += 0x7fffu + ((u >> 16) & 1u);
  return (unsigned short)(u >> 16);
}
__device__ __forceinline__ float bf2f(unsigned short h) {
  union { unsigned u; float f; } v; v.u = ((unsigned)h) << 16;
  return v.f;
}

// async global->LDS, 16B per lane; lds ptr must be wave-uniform base (HW adds lane*16)
__device__ __forceinline__ void load_lds16(const unsigned short* g, unsigned short* l) {
  __builtin_amdgcn_global_load_lds((const __attribute__((address_space(1))) void*)g,
                                   (__attribute__((address_space(3))) void*)l, 16, 0, 0);
}

// ---------------- cast kernel (adds codebook lo-split) ----------------
__global__ void cast_all(const float* __restrict__ x, const float* __restrict__ wq,
                         const float* __restrict__ wk, const float* __restrict__ wv,
                         const float* __restrict__ wo, const float* __restrict__ cb,
                         unsigned short* __restrict__ xb, unsigned short* __restrict__ wb,
                         unsigned short* __restrict__ wob, unsigned short* __restrict__ cbb,
                         unsigned short* __restrict__ cbl, float* __restrict__ lsum) {
  long i = (long)blockIdx.x * blockDim.x + threadIdx.x;
  if (i == 0) lsum[0] = 0.f;
  const long NX = 4194304, NW = 1048576, NCB = 524288;
  const long TOT = NX + 4 * NW + NCB;
  for (long t = i; t < TOT; t += (long)gridDim.x * blockDim.x) {
    if (t < NX) xb[t] = f2bf(x[t]);
    else if (t < NX + NW) wb[t - NX] = f2bf(wq[t - NX]);
    else if (t < NX + 2 * NW) wb[t - NX] = f2bf(wk[t - NX - NW]);
    else if (t < NX + 3 * NW) wb[t - NX] = f2bf(wv[t - NX - 2 * NW]);
    else if (t < NX + 4 * NW) wob[t - NX - 3 * NW] = f2bf(wo[t - NX - 3 * NW]);
    else {
      long idx = t - NX - 4 * NW;
      float v = cb[idx];
      unsigned short hi = f2bf(v);
      cbb[idx] = hi;
      cbl[idx] = f2bf(v - bf2f(hi));
    }
  }
}

// ---------------- codebook norms (fp64 accumulate) ----------------
__global__ void c2_kernel(const float* __restrict__ cb, float* __restrict__ c2) {
  int i = blockIdx.x * blockDim.x + threadIdx.x;
  if (i >= HH * NC) return;
  const float* r = cb + (long)i * HDD;
  double s = 0.0;
  for (int j = 0; j < HDD; j++) s += (double)r[j] * (double)r[j];
  c2[i] = (float)s;
}

// ---------------- GEMM1: Q,V = x * W^T (bf16 MFMA), scatter epilogue ----------------
__global__ __launch_bounds__(256) void gemm_qv(
    const unsigned short* __restrict__ xb, const unsigned short* __restrict__ wb,
    unsigned short* __restrict__ qb, unsigned short* __restrict__ vt) {
  __shared__ __align__(16) unsigned short As[128 * 32];
  __shared__ __align__(16) unsigned short Bs[128 * 32];
  int tid = threadIdx.x;
  int wave = tid >> 6, lane = tid & 63;
  int quad = lane >> 4, col = lane & 15;
  int m0 = blockIdx.y * 128;
  int n0 = blockIdx.x * 128 + (blockIdx.x >= 8 ? 1024 : 0);
  f32x4 acc[4][4] = {};
  int row_in = (wave << 4) + (lane >> 2);
  int seg = lane & 3;
  const unsigned short* gA0 = xb + (long)(m0 + row_in) * DD + seg * 8;
  const unsigned short* gA1 = xb + (long)(m0 + 64 + row_in) * DD + seg * 8;
  const unsigned short* gB0 = wb + (long)(n0 + row_in) * DD + seg * 8;
  const unsigned short* gB1 = wb + (long)(n0 + 64 + row_in) * DD + seg * 8;
  unsigned short* lA0 = As + wave * 512;
  unsigned short* lA1 = As + 2048 + wave * 512;
  unsigned short* lB0 = Bs + wave * 512;
  unsigned short* lB1 = Bs + 2048 + wave * 512;
  int wm = wave & 1, wn = wave >> 1;
  const unsigned short* pa = As + (wm * 64 + col) * 32 + quad * 8;
  const unsigned short* pb = Bs + (wn * 64 + col) * 32 + quad * 8;
  for (int kk = 0; kk < DD; kk += 32) {
    __syncthreads();
    load_lds16(gA0 + kk, lA0);
    load_lds16(gA1 + kk, lA1);
    load_lds16(gB0 + kk, lB0);
    load_lds16(gB1 + kk, lB1);
    __syncthreads();
    bf16x8 af[4], bfr[4];
    for (int t = 0; t < 4; t++) af[t]  = *(const bf16x8*)(pa + t * 512);
    for (int t = 0; t < 4; t++) bfr[t] = *(const bf16x8*)(pb + t * 512);
    for (int mt = 0; mt < 4; mt++)
      for (int nt = 0; nt < 4; nt++)
        acc[mt][nt] = __builtin_amdgcn_mfma_f32_16x16x32_bf16(af[mt], bfr[nt], acc[mt][nt], 0, 0, 0);
  }
  for (int mt = 0; mt < 4; mt++)
    for (int nt = 0; nt < 4; nt++) {
      int mbase = m0 + wm * 64 + mt * 16 + quad * 4;
      int n = n0 + wn * 64 + nt * 16 + col;
      int which = n >> 10, e = n & 1023;
      int h = e >> 6, hd = e & 63;
      for (int r = 0; r < 4; r++) {
        int m = mbase + r;
        int b = m >> 11, l = m & 2047;
        unsigned short val = f2bf(acc[mt][nt][r]);
        long bh = (long)(b * HH + h);
        if (which == 0)      qb[(bh * LL + l) * HDD + hd] = val;
        else                 vt[(bh * HDD + hd) * LL + l] = val;
      }
    }
}

// ---------------- fp32 SGEMM: kf = x * Wk^T; padded LDS + single-sync double buffer ----------------
__global__ __launch_bounds__(256) void kgemm_f32(
    const float* __restrict__ X, const float* __restrict__ W,
    float* __restrict__ kf) {
  __shared__ float As[2][16][132];
  __shared__ float Bs[2][16][68];
  int tid = threadIdx.x;
  int n0 = blockIdx.x * 64;
  int m0 = blockIdx.y * 128;
  int am = tid >> 2;
  int ak4 = (tid & 3) * 4;
  int tn = tid & 15, tm = tid >> 4;
  float acc[8][4] = {};
  const float* pA0 = X + (long)(m0 + am) * DD + ak4;
  const float* pA1 = X + (long)(m0 + 64 + am) * DD + ak4;
  const float* pB  = W + (long)(n0 + am) * DD + ak4;
  float4 xa0 = *(const float4*)(pA0);
  float4 xa1 = *(const float4*)(pA1);
  float4 wb0 = *(const float4*)(pB);
#pragma unroll
  for (int j = 0; j < 4; j++) {
    As[0][ak4 + j][am]      = ((const float*)&xa0)[j];
    As[0][ak4 + j][64 + am] = ((const float*)&xa1)[j];
    Bs[0][ak4 + j][am]      = ((const float*)&wb0)[j];
  }
  __syncthreads();
  for (int k0 = 0; k0 < DD; k0 += 16) {
    int cur = (k0 >> 4) & 1;
    bool more = (k0 + 16 < DD);
    if (more) {
      xa0 = *(const float4*)(pA0 + k0 + 16);
      xa1 = *(const float4*)(pA1 + k0 + 16);
      wb0 = *(const float4*)(pB + k0 + 16);
    }
#pragma unroll
    for (int k = 0; k < 16; k++) {
      float4 a0 = *(const float4*)&As[cur][k][tm * 8];
      float4 a1 = *(const float4*)&As[cur][k][tm * 8 + 4];
      float4 bv = *(const float4*)&Bs[cur][k][tn * 4];
#pragma unroll
      for (int i = 0; i < 4; i++)
#pragma unroll
        for (int j = 0; j < 4; j++) {
          acc[i][j]     = fmaf(((const float*)&a0)[i], ((const float*)&bv)[j], acc[i][j]);
          acc[4 + i][j] = fmaf(((const float*)&a1)[i], ((const float*)&bv)[j], acc[4 + i][j]);
        }
    }
    if (more) {
#pragma unroll
      for (int j = 0; j < 4; j++) {
        As[cur ^ 1][ak4 + j][am]      = ((const float*)&xa0)[j];
        As[cur ^ 1][ak4 + j][64 + am] = ((const float*)&xa1)[j];
        Bs[cur ^ 1][ak4 + j][am]      = ((const float*)&wb0)[j];
      }
      __syncthreads();
    }
  }
  int h = n0 >> 6;
#pragma unroll
  for (int i = 0; i < 8; i++) {
    int m = m0 + tm * 8 + i;
    int b = m >> 11, l = m & 2047;
    float4 o;
    ((float*)&o)[0] = acc[i][0]; ((float*)&o)[1] = acc[i][1];
    ((float*)&o)[2] = acc[i][2]; ((float*)&o)[3] = acc[i][3];
    *(float4*)(kf + (((long)(b * HH + h) * LL + l) * HDD) + tn * 4) = o;
  }
}

// ---------------- VQ via split-bf16 MFMA + margin-gated fp32 rescore ----------------
__global__ __launch_bounds__(256) void vq_mfma(
    const float* __restrict__ kf, const float* __restrict__ cb,
    const float* __restrict__ c2, const unsigned short* __restrict__ cbb,
    const unsigned short* __restrict__ cbl,
    unsigned short* __restrict__ khat, float* __restrict__ scodes,
    float* __restrict__ lsum) {
  __shared__ int finalIdx[64];
  int tid = threadIdx.x, wave = tid >> 6, lane = tid & 63;
  int quad = lane >> 4, col = lane & 15;
  int rb = blockIdx.x;
  int bh = blockIdx.y;
  int h = bh & 15;
  int rbase = rb * 64 + wave * 16;
  const float* kp = kf + ((long)bh * LL + rbase + col) * HDD + quad * 8;
  float fv[16];
  {
    float4 t0 = *(const float4*)(kp);
    float4 t1 = *(const float4*)(kp + 4);
    float4 t2 = *(const float4*)(kp + 32);
    float4 t3 = *(const float4*)(kp + 36);
    fv[0]=t0.x; fv[1]=t0.y; fv[2]=t0.z; fv[3]=t0.w;
    fv[4]=t1.x; fv[5]=t1.y; fv[6]=t1.z; fv[7]=t1.w;
    fv[8]=t2.x; fv[9]=t2.y; fv[10]=t2.z; fv[11]=t2.w;
    fv[12]=t3.x; fv[13]=t3.y; fv[14]=t3.z; fv[15]=t3.w;
  }
  float k2 = 0.f;
#pragma unroll
  for (int j = 0; j < 16; j++) k2 = fmaf(fv[j], fv[j], k2);
  k2 += __shfl_xor(k2, 16);
  k2 += __shfl_xor(k2, 32);
  u16x8 kh0u, kh1u, kl0u, kl1u;
#pragma unroll
  for (int j = 0; j < 8; j++) {
    unsigned short hi = f2bf(fv[j]);
    kh0u[j] = hi; kl0u[j] = f2bf(fv[j] - bf2f(hi));
    unsigned short hi2 = f2bf(fv[8 + j]);
    kh1u[j] = hi2; kl1u[j] = f2bf(fv[8 + j] - bf2f(hi2));
  }
  bf16x8 bh0 = __builtin_bit_cast(bf16x8, kh0u);
  bf16x8 bh1 = __builtin_bit_cast(bf16x8, kh1u);
  bf16x8 bl0 = __builtin_bit_cast(bf16x8, kl0u);
  bf16x8 bl1 = __builtin_bit_cast(bf16x8, kl1u);
  const unsigned short* cbbh = cbb + (long)h * NC * HDD;
  const unsigned short* cblh = cbl + (long)h * NC * HDD;
  const float* c2h = c2 + h * NC;
  float b1v = 1e38f, b2v = 1e38f;
  int b1i = 0x7fffffff, b2i = 0x7fffffff;
  for (int ch = 0; ch < 32; ch++) {
    long base = (long)(ch * 16 + col) * HDD + quad * 8;
    bf16x8 ah0 = *(const bf16x8*)(cbbh + base);
    bf16x8 ah1 = *(const bf16x8*)(cbbh + base + 32);
    bf16x8 al0 = *(const bf16x8*)(cblh + base);
    bf16x8 al1 = *(const bf16x8*)(cblh + base + 32);
    f32x4 acc = {};
    acc = __builtin_amdgcn_mfma_f32_16x16x32_bf16(ah0, bh0, acc, 0, 0, 0);
    acc = __builtin_amdgcn_mfma_f32_16x16x32_bf16(ah1, bh1, acc, 0, 0, 0);
    acc = __builtin_amdgcn_mfma_f32_16x16x32_bf16(al0, bh0, acc, 0, 0, 0);
    acc = __builtin_amdgcn_mfma_f32_16x16x32_bf16(al1, bh1, acc, 0, 0, 0);
    acc = __builtin_amdgcn_mfma_f32_16x16x32_bf16(ah0, bl0, acc, 0, 0, 0);
    acc = __builtin_amdgcn_mfma_f32_16x16x32_bf16(ah1, bl1, acc, 0, 0, 0);
    f32x4 c2v = *(const f32x4*)(c2h + ch * 16 + quad * 4);
#pragma unroll
    for (int r = 0; r < 4; r++) {
      float val = c2v[r] - 2.0f * acc[r];
      int idx = ch * 16 + quad * 4 + r;
      if (val < b1v || (val == b1v && idx < b1i)) {
        b2v = b1v; b2i = b1i; b1v = val; b1i = idx;
      } else if (val < b2v || (val == b2v && idx < b2i)) {
        b2v = val; b2i = idx;
      }
    }
  }
#pragma unroll
  for (int d = 16; d <= 32; d <<= 1) {
    float o1v = __shfl_xor(b1v, d); int o1i = __shfl_xor(b1i, d);
    float o2v = __shfl_xor(b2v, d); int o2i = __shfl_xor(b2i, d);
    if (o1v < b1v || (o1v == b1v && o1i < b1i)) {
      float nv; int ni;
      if (b1v < o2v || (b1v == o2v && b1i < o2i)) { nv = b1v; ni = b1i; }
      else { nv = o2v; ni = o2i; }
      b1v = o1v; b1i = o1i; b2v = nv; b2i = ni;
    } else {
      if (o1v < b2v || (o1v == b2v && o1i < b2i)) { b2v = o1v; b2i = o1i; }
    }
  }
  const float DMARG = 0.015625f;
  float part = 0.f;
  int widx = b1i;
  if (lane < 16) {
    if (b2v - b1v > DMARG) {
      part = k2 + b1v;
    } else {
      const float* krow = kf + ((long)bh * LL + rbase + lane) * HDD;
      const float* c1p = cb + ((long)h * NC + b1i) * HDD;
      const float* c2p = cb + ((long)h * NC + b2i) * HDD;
      float s1 = 0.f, s2 = 0.f;
      for (int j = 0; j < HDD; j++) {
        float kv = krow[j];
        float d1 = kv - c1p[j]; s1 = fmaf(d1, d1, s1);
        float d2 = kv - c2p[j]; s2 = fmaf(d2, d2, s2);
      }
      if (s2 < s1 || (s2 == s1 && b2i < b1i)) { widx = b2i; part = s2; }
      else { widx = b1i; part = s1; }
    }
  }
  part += __shfl_xor(part, 1);  part += __shfl_xor(part, 2);
  part += __shfl_xor(part, 4);  part += __shfl_xor(part, 8);
  part += __shfl_xor(part, 16); part += __shfl_xor(part, 32);
  if (lane == 0) atomicAdd(lsum, part);
  if (lane < 16) {
    scodes[(long)bh * LL + rbase + lane] = (float)widx;
    finalIdx[wave * 16 + lane] = widx;
  }
  __syncthreads();
  {
    int r = tid >> 2, p = (tid & 3) * 16;
    int code = finalIdx[r];
    const unsigned short* src = cbb + ((long)h * NC + code) * HDD + p;
    unsigned short* dst = khat + ((long)bh * LL + rb * 64 + r) * HDD + p;
    *(u16x8*)(dst)     = *(const u16x8*)(src);
    *(u16x8*)(dst + 8) = *(const u16x8*)(src + 8);
  }
}

// ---------------- flash attention partials: paired q-tiles, K-range split by blockIdx.z ----------------
// Per-wave body identical to the verified round-6 kernel; epilogue writes raw partials.
__global__ __launch_bounds__(256) void attn_part(
    const unsigned short* __restrict__ qb, const unsigned short* __restrict__ khat,
    const unsigned short* __restrict__ vt, float* __restrict__ opart,
    float* __restrict__ lpart) {
  __shared__ __align__(16) unsigned short Pbuf[4][2][16 * 72];
  int tid = threadIdx.x, wave = tid >> 6, lane = tid & 63;
  int quad = lane >> 4, col = lane & 15;
  int pi = blockIdx.x;          // 0..15: pairs q-tile pi with 31-pi
  int bh = blockIdx.y;
  int z = blockIdx.z;           // 0/1: K-range half
  int ta = pi, tb = 31 - pi;
  int half = (tb + 2) >> 1;
  int k_lo = z ? half : 0;
  int k_hi = z ? tb + 1 : half;
  int qbA = ta * 64 + wave * 16;
  int qbB = tb * 64 + wave * 16;
  const unsigned short* qrA = qb + ((long)bh * LL + qbA + col) * HDD;
  const unsigned short* qrB = qb + ((long)bh * LL + qbB + col) * HDD;
  bf16x8 aqA0 = *(const bf16x8*)(qrA + quad * 8);
  bf16x8 aqA1 = *(const bf16x8*)(qrA + 32 + quad * 8);
  bf16x8 aqB0 = *(const bf16x8*)(qrB + quad * 8);
  bf16x8 aqB1 = *(const bf16x8*)(qrB + 32 + quad * 8);
  float lA[4] = {0.f, 0.f, 0.f, 0.f}, lB[4] = {0.f, 0.f, 0.f, 0.f};
  f32x4 oA[4] = {}, oB[4] = {};
  unsigned short* PA = Pbuf[wave][0];
  unsigned short* PB = Pbuf[wave][1];
  const unsigned short* kh = khat + (long)bh * LL * HDD;
  const unsigned short* vh = vt + (long)bh * HDD * LL;
  const float SCL = 0.18033688011112042f;  // log2(e) / 8
  for (int kt = k_lo; kt < k_hi; kt++) {
    int kbase = kt * 64;
    bool actA = (kt <= ta);
    f32x4 zA[4], zB[4];
    for (int nt = 0; nt < 4; nt++) {
      const unsigned short* krow = kh + (long)(kbase + nt * 16 + col) * HDD;
      bf16x8 k0 = *(const bf16x8*)(krow + quad * 8);
      bf16x8 k1 = *(const bf16x8*)(krow + 32 + quad * 8);
      f32x4 zz = {};
      zz = __builtin_amdgcn_mfma_f32_16x16x32_bf16(aqB0, k0, zz, 0, 0, 0);
      zz = __builtin_amdgcn_mfma_f32_16x16x32_bf16(aqB1, k1, zz, 0, 0, 0);
      zB[nt] = zz;
      if (actA) {
        f32x4 y = {};
        y = __builtin_amdgcn_mfma_f32_16x16x32_bf16(aqA0, k0, y, 0, 0, 0);
        y = __builtin_amdgcn_mfma_f32_16x16x32_bf16(aqA1, k1, y, 0, 0, 0);
        zA[nt] = y;
      }
    }
    for (int nt = 0; nt < 4; nt++) {
      int key = kbase + nt * 16 + col;
      for (int r = 0; r < 4; r++) {
        float sc = zB[nt][r] * SCL;
        if (kt == tb && key > qbB + quad * 4 + r) sc = -1e30f;
        float p = exp2f(sc);
        lB[r] += p;
        PB[(quad * 4 + r) * 72 + nt * 16 + col] = f2bf(p);
      }
    }
    if (actA) {
      for (int nt = 0; nt < 4; nt++) {
        int key = kbase + nt * 16 + col;
        for (int r = 0; r < 4; r++) {
          float sc = zA[nt][r] * SCL;
          if (kt == ta && key > qbA + quad * 4 + r) sc = -1e30f;
          float p = exp2f(sc);
          lA[r] += p;
          PA[(quad * 4 + r) * 72 + nt * 16 + col] = f2bf(p);
        }
      }
    }
    bf16x8 apB0 = *(const bf16x8*)(PB + col * 72 + quad * 8);
    bf16x8 apB1 = *(const bf16x8*)(PB + col * 72 + 32 + quad * 8);
    bf16x8 apA0, apA1;
    if (actA) {
      apA0 = *(const bf16x8*)(PA + col * 72 + quad * 8);
      apA1 = *(const bf16x8*)(PA + col * 72 + 32 + quad * 8);
    }
    for (int nt = 0; nt < 4; nt++) {
      const unsigned short* vrow = vh + (long)(nt * 16 + col) * LL + kbase;
      bf16x8 v0 = *(const bf16x8*)(vrow + quad * 8);
      bf16x8 v1 = *(const bf16x8*)(vrow + 32 + quad * 8);
      oB[nt] = __builtin_amdgcn_mfma_f32_16x16x32_bf16(apB0, v0, oB[nt], 0, 0, 0);
      oB[nt] = __builtin_amdgcn_mfma_f32_16x16x32_bf16(apB1, v1, oB[nt], 0, 0, 0);
      if (actA) {
        oA[nt] = __builtin_amdgcn_mfma_f32_16x16x32_bf16(apA0, v0, oA[nt], 0, 0, 0);
        oA[nt] = __builtin_amdgcn_mfma_f32_16x16x32_bf16(apA1, v1, oA[nt], 0, 0, 0);
      }
    }
  }
  // per-row sums (16 lanes per row), then store raw partials
  float lAr[4], lBr[4];
  for (int r = 0; r < 4; r++) {
    float t = lA[r];
    t += __shfl_xor(t, 1); t += __shfl_xor(t, 2);
    t += __shfl_xor(t, 4); t += __shfl_xor(t, 8);
    lAr[r] = t;
    float u = lB[r];
    u += __shfl_xor(u, 1); u += __shfl_xor(u, 2);
    u += __shfl_xor(u, 4); u += __shfl_xor(u, 8);
    lBr[r] = u;
  }
  float* oz = opart + ((long)z * 32 + bh) * LL * HDD;
  float* lz = lpart + ((long)z * 32 + bh) * LL;
  for (int r = 0; r < 4; r++) {
    int rowA = qbA + quad * 4 + r;
    int rowB = qbB + quad * 4 + r;
    for (int nt = 0; nt < 4; nt++) {
      int hd = nt * 16 + col;
      oz[(long)rowA * HDD + hd] = oA[nt][r];
      oz[(long)rowB * HDD + hd] = oB[nt][r];
    }
    if (col == 0) {
      lz[rowA] = lAr[r];
      lz[rowB] = lBr[r];
    }
  }
}

// ---------------- merge halves, normalize, write attnb (bf16) ----------------
__global__ void attn_merge(const float* __restrict__ opart,
                           const float* __restrict__ lpart,
                           unsigned short* __restrict__ attnb) {
  int t = blockIdx.x * blockDim.x + threadIdx.x;   // 1,048,576 threads
  long g = (long)t * 4;
  int bhl = (int)(g >> 6);
  int hd = (int)(g & 63);
  int bh = bhl >> 11, l = bhl & 2047;
  int b = bh >> 4, h = bh & 15;
  long o0 = (long)bhl * HDD + hd;
  long o1 = o0 + (long)32 * LL * HDD;
  float4 v0 = *(const float4*)(opart + o0);
  float4 v1 = *(const float4*)(opart + o1);
  float linv = 1.0f / (lpart[bhl] + lpart[bhl + 32 * LL]);
  u16x4 res;
  res[0] = f2bf((v0.x + v1.x) * linv);
  res[1] = f2bf((v0.y + v1.y) * linv);
  res[2] = f2bf((v0.z + v1.z) * linv);
  res[3] = f2bf((v0.w + v1.w) * linv);
  *(u16x4*)(attnb + ((long)b * LL + l) * DD + h * HDD + hd) = res;
}

// ---------------- GEMM2: out = attn * Wo^T (fp32 store) ----------------
__global__ __launch_bounds__(256) void gemm_out(
    const unsigned short* __restrict__ attnb, const unsigned short* __restrict__ wob,
    float* __restrict__ out) {
  __shared__ __align__(16) unsigned short As[128 * 32];
  __shared__ __align__(16) unsigned short Bs[128 * 32];
  int tid = threadIdx.x;
  int wave = tid >> 6, lane = tid & 63;
  int quad = lane >> 4, col = lane & 15;
  int m0 = blockIdx.y * 128;
  int n0 = blockIdx.x * 128;
  f32x4 acc[4][4] = {};
  int row_in = (wave << 4) + (lane >> 2);
  int seg = lane & 3;
  const unsigned short* gA0 = attnb + (long)(m0 + row_in) * DD + seg * 8;
  const unsigned short* gA1 = attnb + (long)(m0 + 64 + row_in) * DD + seg * 8;
  const unsigned short* gB0 = wob + (long)(n0 + row_in) * DD + seg * 8;
  const unsigned short* gB1 = wob + (long)(n0 + 64 + row_in) * DD + seg * 8;
  unsigned short* lA0 = As + wave * 512;
  unsigned short* lA1 = As + 2048 + wave * 512;
  unsigned short* lB0 = Bs + wave * 512;
  unsigned short* lB1 = Bs + 2048 + wave * 512;
  int wm = wave & 1, wn = wave >> 1;
  const unsigned short* pa = As + (wm * 64 + col) * 32 + quad * 8;
  const unsigned short* pb = Bs + (wn * 64 + col) * 32 + quad * 8;
  for (int kk = 0; kk < DD; kk += 32) {
    __syncthreads();
    load_lds16(gA0 + kk, lA0);
    load_lds16(gA1 + kk, lA1);
    load_lds16(gB0 + kk, lB0);
    load_lds16(gB1 + kk, lB1);
    __syncthreads();
    bf16x8 af[4], bfr[4];
    for (int t = 0; t < 4; t++) af[t]  = *(const bf16x8*)(pa + t * 512);
    for (int t = 0; t < 4; t++) bfr[t] = *(const bf16x8*)(pb + t * 512);
    for (int mt = 0; mt < 4; mt++)
      for (int nt = 0; nt < 4; nt++)
        acc[mt][nt] = __builtin_amdgcn_mfma_f32_16x16x32_bf16(af[mt], bfr[nt], acc[mt][nt], 0, 0, 0);
  }
  for (int mt = 0; mt < 4; mt++)
    for (int nt = 0; nt < 4; nt++) {
      int mbase = m0 + wm * 64 + mt * 16 + quad * 4;
      int n = n0 + wn * 64 + nt * 16 + col;
      for (int r = 0; r < 4; r++)
        out[(long)(mbase + r) * DD + n] = acc[mt][nt][r];
    }
}

// ---------------- finalize scalars ----------------
__global__ void finalize(const float* __restrict__ lsum, float* __restrict__ out) {
  if (threadIdx.x == 0) {
    float v = lsum[0] / (float)(BB * HH * LL);
    out[4194304] = v;
    out[4194305] = v;
  }
}

extern "C" void kernel_launch(void* const* d_in, const int* in_sizes, int n_in,
                              void* d_out, int out_size, void* d_ws, size_t ws_size,
                              hipStream_t stream) {
  const float* x  = (const float*)d_in[0];
  const float* wq = (const float*)d_in[1];
  const float* wk = (const float*)d_in[2];
  const float* wv = (const float*)d_in[3];
  const float* wo = (const float*)d_in[4];
  const float* cb = (const float*)d_in[5];
  float* out = (float*)d_out;

  char* ws = (char*)d_ws;
  size_t off = 0;
  auto alloc = [&](size_t bytes) {
    void* p = ws + off;
    off = (off + bytes + 255) & ~(size_t)255;
    return p;
  };
  unsigned short* xb    = (unsigned short*)alloc(4194304 * 2);
  unsigned short* wb    = (unsigned short*)alloc(3145728 * 2);
  unsigned short* wob   = (unsigned short*)alloc(1048576 * 2);
  unsigned short* cbb   = (unsigned short*)alloc(524288 * 2);
  unsigned short* cbl   = (unsigned short*)alloc(524288 * 2);
  unsigned short* qb    = (unsigned short*)alloc(4194304 * 2);
  unsigned short* vt    = (unsigned short*)alloc(4194304 * 2);
  unsigned short* khat  = (unsigned short*)alloc(4194304 * 2);
  unsigned short* attnb = (unsigned short*)alloc(4194304 * 2);
  float* kf    = (float*)alloc(4194304 * 4);
  float* opart = (float*)alloc((size_t)2 * 32 * LL * HDD * 4);
  float* lpart = (float*)alloc((size_t)2 * 32 * LL * 4);
  float* c2   = (float*)alloc(8192 * 4);
  float* lsum = (float*)alloc(256);

  cast_all<<<dim3(4096), dim3(256), 0, stream>>>(x, wq, wk, wv, wo, cb, xb, wb, wob, cbb, cbl, lsum);
  c2_kernel<<<dim3(32), dim3(256), 0, stream>>>(cb, c2);
  gemm_qv<<<dim3(16, 32), dim3(256), 0, stream>>>(xb, wb, qb, vt);
  kgemm_f32<<<dim3(16, 32), dim3(256), 0, stream>>>(x, wk, kf);
  vq_mfma<<<dim3(32, 32), dim3(256), 0, stream>>>(kf, cb, c2, cbb, cbl, khat, out + 4194306, lsum);
  attn_part<<<dim3(16, 32, 2), dim3(256), 0, stream>>>(qb, khat, vt, opart, lpart);
  attn_merge<<<dim3(4096), dim3(256), 0, stream>>>(opart, lpart, attnb);
  gemm_out<<<dim3(8, 32), dim3(256), 0, stream>>>(attnb, wob, out);
  finalize<<<dim3(1), dim3(64), 0, stream>>>(lsum, out);
}

// Round 10
// 441.287 us; speedup vs baseline: 1.1967x; 1.1967x over previous
//
#include <hip/hip_runtime.h>
#include <stdint.h>

#define BB 2
#define HH 16
#define LL 2048
#define DD 1024
#define HDD 64
#define NC 512

typedef __bf16 bf16x8 __attribute__((ext_vector_type(8)));
typedef float f32x4 __attribute__((ext_vector_type(4)));
typedef unsigned short u16x8 __attribute__((ext_vector_type(8)));

__device__ __forceinline__ unsigned short f2bf(float f) {
  union { float f; unsigned u; } v; v.f = f;
  unsigned u = v.u;
  u += 0x7fffu + ((u >> 16) & 1u);
  return (unsigned short)(u >> 16);
}
__device__ __forceinline__ float bf2f(unsigned short h) {
  union { unsigned u; float f; } v; v.u = ((unsigned)h) << 16;
  return v.f;
}

// async global->LDS, 16B per lane; lds ptr must be wave-uniform base (HW adds lane*16)
__device__ __forceinline__ void load_lds16(const unsigned short* g, unsigned short* l) {
  __builtin_amdgcn_global_load_lds((const __attribute__((address_space(1))) void*)g,
                                   (__attribute__((address_space(3))) void*)l, 16, 0, 0);
}

// ---------------- cast kernel (adds codebook lo-split) ----------------
__global__ void cast_all(const float* __restrict__ x, const float* __restrict__ wq,
                         const float* __restrict__ wk, const float* __restrict__ wv,
                         const float* __restrict__ wo, const float* __restrict__ cb,
                         unsigned short* __restrict__ xb, unsigned short* __restrict__ wb,
                         unsigned short* __restrict__ wob, unsigned short* __restrict__ cbb,
                         unsigned short* __restrict__ cbl, float* __restrict__ lsum) {
  long i = (long)blockIdx.x * blockDim.x + threadIdx.x;
  if (i == 0) lsum[0] = 0.f;
  const long NX = 4194304, NW = 1048576, NCB = 524288;
  const long TOT = NX + 4 * NW + NCB;
  for (long t = i; t < TOT; t += (long)gridDim.x * blockDim.x) {
    if (t < NX) xb[t] = f2bf(x[t]);
    else if (t < NX + NW) wb[t - NX] = f2bf(wq[t - NX]);
    else if (t < NX + 2 * NW) wb[t - NX] = f2bf(wk[t - NX - NW]);
    else if (t < NX + 3 * NW) wb[t - NX] = f2bf(wv[t - NX - 2 * NW]);
    else if (t < NX + 4 * NW) wob[t - NX - 3 * NW] = f2bf(wo[t - NX - 3 * NW]);
    else {
      long idx = t - NX - 4 * NW;
      float v = cb[idx];
      unsigned short hi = f2bf(v);
      cbb[idx] = hi;
      cbl[idx] = f2bf(v - bf2f(hi));
    }
  }
}

// ---------------- codebook norms (fp64 accumulate) ----------------
__global__ void c2_kernel(const float* __restrict__ cb, float* __restrict__ c2) {
  int i = blockIdx.x * blockDim.x + threadIdx.x;
  if (i >= HH * NC) return;
  const float* r = cb + (long)i * HDD;
  double s = 0.0;
  for (int j = 0; j < HDD; j++) s += (double)r[j] * (double)r[j];
  c2[i] = (float)s;
}

// ---------------- GEMM1: Q,V = x * W^T (bf16 MFMA), scatter epilogue ----------------
__global__ __launch_bounds__(256) void gemm_qv(
    const unsigned short* __restrict__ xb, const unsigned short* __restrict__ wb,
    unsigned short* __restrict__ qb, unsigned short* __restrict__ vt) {
  __shared__ __align__(16) unsigned short As[128 * 32];
  __shared__ __align__(16) unsigned short Bs[128 * 32];
  int tid = threadIdx.x;
  int wave = tid >> 6, lane = tid & 63;
  int quad = lane >> 4, col = lane & 15;
  int m0 = blockIdx.y * 128;
  int n0 = blockIdx.x * 128 + (blockIdx.x >= 8 ? 1024 : 0);
  f32x4 acc[4][4] = {};
  int row_in = (wave << 4) + (lane >> 2);
  int seg = lane & 3;
  const unsigned short* gA0 = xb + (long)(m0 + row_in) * DD + seg * 8;
  const unsigned short* gA1 = xb + (long)(m0 + 64 + row_in) * DD + seg * 8;
  const unsigned short* gB0 = wb + (long)(n0 + row_in) * DD + seg * 8;
  const unsigned short* gB1 = wb + (long)(n0 + 64 + row_in) * DD + seg * 8;
  unsigned short* lA0 = As + wave * 512;
  unsigned short* lA1 = As + 2048 + wave * 512;
  unsigned short* lB0 = Bs + wave * 512;
  unsigned short* lB1 = Bs + 2048 + wave * 512;
  int wm = wave & 1, wn = wave >> 1;
  const unsigned short* pa = As + (wm * 64 + col) * 32 + quad * 8;
  const unsigned short* pb = Bs + (wn * 64 + col) * 32 + quad * 8;
  for (int kk = 0; kk < DD; kk += 32) {
    __syncthreads();
    load_lds16(gA0 + kk, lA0);
    load_lds16(gA1 + kk, lA1);
    load_lds16(gB0 + kk, lB0);
    load_lds16(gB1 + kk, lB1);
    __syncthreads();
    bf16x8 af[4], bfr[4];
    for (int t = 0; t < 4; t++) af[t]  = *(const bf16x8*)(pa + t * 512);
    for (int t = 0; t < 4; t++) bfr[t] = *(const bf16x8*)(pb + t * 512);
    for (int mt = 0; mt < 4; mt++)
      for (int nt = 0; nt < 4; nt++)
        acc[mt][nt] = __builtin_amdgcn_mfma_f32_16x16x32_bf16(af[mt], bfr[nt], acc[mt][nt], 0, 0, 0);
  }
  for (int mt = 0; mt < 4; mt++)
    for (int nt = 0; nt < 4; nt++) {
      int mbase = m0 + wm * 64 + mt * 16 + quad * 4;
      int n = n0 + wn * 64 + nt * 16 + col;
      int which = n >> 10, e = n & 1023;
      int h = e >> 6, hd = e & 63;
      for (int r = 0; r < 4; r++) {
        int m = mbase + r;
        int b = m >> 11, l = m & 2047;
        unsigned short val = f2bf(acc[mt][nt][r]);
        long bh = (long)(b * HH + h);
        if (which == 0)      qb[(bh * LL + l) * HDD + hd] = val;
        else                 vt[(bh * HDD + hd) * LL + l] = val;
      }
    }
}

// ---------------- fp32 SGEMM: kf = x * Wk^T; padded LDS + single-sync double buffer ----------------
__global__ __launch_bounds__(256) void kgemm_f32(
    const float* __restrict__ X, const float* __restrict__ W,
    float* __restrict__ kf) {
  __shared__ float As[2][16][132];
  __shared__ float Bs[2][16][68];
  int tid = threadIdx.x;
  int n0 = blockIdx.x * 64;
  int m0 = blockIdx.y * 128;
  int am = tid >> 2;
  int ak4 = (tid & 3) * 4;
  int tn = tid & 15, tm = tid >> 4;
  float acc[8][4] = {};
  const float* pA0 = X + (long)(m0 + am) * DD + ak4;
  const float* pA1 = X + (long)(m0 + 64 + am) * DD + ak4;
  const float* pB  = W + (long)(n0 + am) * DD + ak4;
  float4 xa0 = *(const float4*)(pA0);
  float4 xa1 = *(const float4*)(pA1);
  float4 wb0 = *(const float4*)(pB);
#pragma unroll
  for (int j = 0; j < 4; j++) {
    As[0][ak4 + j][am]      = ((const float*)&xa0)[j];
    As[0][ak4 + j][64 + am] = ((const float*)&xa1)[j];
    Bs[0][ak4 + j][am]      = ((const float*)&wb0)[j];
  }
  __syncthreads();
  for (int k0 = 0; k0 < DD; k0 += 16) {
    int cur = (k0 >> 4) & 1;
    bool more = (k0 + 16 < DD);
    if (more) {
      xa0 = *(const float4*)(pA0 + k0 + 16);
      xa1 = *(const float4*)(pA1 + k0 + 16);
      wb0 = *(const float4*)(pB + k0 + 16);
    }
#pragma unroll
    for (int k = 0; k < 16; k++) {
      float4 a0 = *(const float4*)&As[cur][k][tm * 8];
      float4 a1 = *(const float4*)&As[cur][k][tm * 8 + 4];
      float4 bv = *(const float4*)&Bs[cur][k][tn * 4];
#pragma unroll
      for (int i = 0; i < 4; i++)
#pragma unroll
        for (int j = 0; j < 4; j++) {
          acc[i][j]     = fmaf(((const float*)&a0)[i], ((const float*)&bv)[j], acc[i][j]);
          acc[4 + i][j] = fmaf(((const float*)&a1)[i], ((const float*)&bv)[j], acc[4 + i][j]);
        }
    }
    if (more) {
#pragma unroll
      for (int j = 0; j < 4; j++) {
        As[cur ^ 1][ak4 + j][am]      = ((const float*)&xa0)[j];
        As[cur ^ 1][ak4 + j][64 + am] = ((const float*)&xa1)[j];
        Bs[cur ^ 1][ak4 + j][am]      = ((const float*)&wb0)[j];
      }
      __syncthreads();
    }
  }
  int h = n0 >> 6;
#pragma unroll
  for (int i = 0; i < 8; i++) {
    int m = m0 + tm * 8 + i;
    int b = m >> 11, l = m & 2047;
    float4 o;
    ((float*)&o)[0] = acc[i][0]; ((float*)&o)[1] = acc[i][1];
    ((float*)&o)[2] = acc[i][2]; ((float*)&o)[3] = acc[i][3];
    *(float4*)(kf + (((long)(b * HH + h) * LL + l) * HDD) + tn * 4) = o;
  }
}

// ---------------- VQ via split-bf16 MFMA + margin-gated fp32 rescore ----------------
__global__ __launch_bounds__(256) void vq_mfma(
    const float* __restrict__ kf, const float* __restrict__ cb,
    const float* __restrict__ c2, const unsigned short* __restrict__ cbb,
    const unsigned short* __restrict__ cbl,
    unsigned short* __restrict__ khat, float* __restrict__ scodes,
    float* __restrict__ lsum) {
  __shared__ int finalIdx[64];
  int tid = threadIdx.x, wave = tid >> 6, lane = tid & 63;
  int quad = lane >> 4, col = lane & 15;
  int rb = blockIdx.x;
  int bh = blockIdx.y;
  int h = bh & 15;
  int rbase = rb * 64 + wave * 16;
  const float* kp = kf + ((long)bh * LL + rbase + col) * HDD + quad * 8;
  float fv[16];
  {
    float4 t0 = *(const float4*)(kp);
    float4 t1 = *(const float4*)(kp + 4);
    float4 t2 = *(const float4*)(kp + 32);
    float4 t3 = *(const float4*)(kp + 36);
    fv[0]=t0.x; fv[1]=t0.y; fv[2]=t0.z; fv[3]=t0.w;
    fv[4]=t1.x; fv[5]=t1.y; fv[6]=t1.z; fv[7]=t1.w;
    fv[8]=t2.x; fv[9]=t2.y; fv[10]=t2.z; fv[11]=t2.w;
    fv[12]=t3.x; fv[13]=t3.y; fv[14]=t3.z; fv[15]=t3.w;
  }
  float k2 = 0.f;
#pragma unroll
  for (int j = 0; j < 16; j++) k2 = fmaf(fv[j], fv[j], k2);
  k2 += __shfl_xor(k2, 16);
  k2 += __shfl_xor(k2, 32);
  u16x8 kh0u, kh1u, kl0u, kl1u;
#pragma unroll
  for (int j = 0; j < 8; j++) {
    unsigned short hi = f2bf(fv[j]);
    kh0u[j] = hi; kl0u[j] = f2bf(fv[j] - bf2f(hi));
    unsigned short hi2 = f2bf(fv[8 + j]);
    kh1u[j] = hi2; kl1u[j] = f2bf(fv[8 + j] - bf2f(hi2));
  }
  bf16x8 bh0 = __builtin_bit_cast(bf16x8, kh0u);
  bf16x8 bh1 = __builtin_bit_cast(bf16x8, kh1u);
  bf16x8 bl0 = __builtin_bit_cast(bf16x8, kl0u);
  bf16x8 bl1 = __builtin_bit_cast(bf16x8, kl1u);
  const unsigned short* cbbh = cbb + (long)h * NC * HDD;
  const unsigned short* cblh = cbl + (long)h * NC * HDD;
  const float* c2h = c2 + h * NC;
  float b1v = 1e38f, b2v = 1e38f;
  int b1i = 0x7fffffff, b2i = 0x7fffffff;
  for (int ch = 0; ch < 32; ch++) {
    long base = (long)(ch * 16 + col) * HDD + quad * 8;
    bf16x8 ah0 = *(const bf16x8*)(cbbh + base);
    bf16x8 ah1 = *(const bf16x8*)(cbbh + base + 32);
    bf16x8 al0 = *(const bf16x8*)(cblh + base);
    bf16x8 al1 = *(const bf16x8*)(cblh + base + 32);
    f32x4 acc = {};
    acc = __builtin_amdgcn_mfma_f32_16x16x32_bf16(ah0, bh0, acc, 0, 0, 0);
    acc = __builtin_amdgcn_mfma_f32_16x16x32_bf16(ah1, bh1, acc, 0, 0, 0);
    acc = __builtin_amdgcn_mfma_f32_16x16x32_bf16(al0, bh0, acc, 0, 0, 0);
    acc = __builtin_amdgcn_mfma_f32_16x16x32_bf16(al1, bh1, acc, 0, 0, 0);
    acc = __builtin_amdgcn_mfma_f32_16x16x32_bf16(ah0, bl0, acc, 0, 0, 0);
    acc = __builtin_amdgcn_mfma_f32_16x16x32_bf16(ah1, bl1, acc, 0, 0, 0);
    f32x4 c2v = *(const f32x4*)(c2h + ch * 16 + quad * 4);
#pragma unroll
    for (int r = 0; r < 4; r++) {
      float val = c2v[r] - 2.0f * acc[r];
      int idx = ch * 16 + quad * 4 + r;
      if (val < b1v || (val == b1v && idx < b1i)) {
        b2v = b1v; b2i = b1i; b1v = val; b1i = idx;
      } else if (val < b2v || (val == b2v && idx < b2i)) {
        b2v = val; b2i = idx;
      }
    }
  }
#pragma unroll
  for (int d = 16; d <= 32; d <<= 1) {
    float o1v = __shfl_xor(b1v, d); int o1i = __shfl_xor(b1i, d);
    float o2v = __shfl_xor(b2v, d); int o2i = __shfl_xor(b2i, d);
    if (o1v < b1v || (o1v == b1v && o1i < b1i)) {
      float nv; int ni;
      if (b1v < o2v || (b1v == o2v && b1i < o2i)) { nv = b1v; ni = b1i; }
      else { nv = o2v; ni = o2i; }
      b1v = o1v; b1i = o1i; b2v = nv; b2i = ni;
    } else {
      if (o1v < b2v || (o1v == b2v && o1i < b2i)) { b2v = o1v; b2i = o1i; }
    }
  }
  const float DMARG = 0.015625f;
  float part = 0.f;
  int widx = b1i;
  if (lane < 16) {
    if (b2v - b1v > DMARG) {
      part = k2 + b1v;
    } else {
      const float* krow = kf + ((long)bh * LL + rbase + lane) * HDD;
      const float* c1p = cb + ((long)h * NC + b1i) * HDD;
      const float* c2p = cb + ((long)h * NC + b2i) * HDD;
      float s1 = 0.f, s2 = 0.f;
      for (int j = 0; j < HDD; j++) {
        float kv = krow[j];
        float d1 = kv - c1p[j]; s1 = fmaf(d1, d1, s1);
        float d2 = kv - c2p[j]; s2 = fmaf(d2, d2, s2);
      }
      if (s2 < s1 || (s2 == s1 && b2i < b1i)) { widx = b2i; part = s2; }
      else { widx = b1i; part = s1; }
    }
  }
  part += __shfl_xor(part, 1);  part += __shfl_xor(part, 2);
  part += __shfl_xor(part, 4);  part += __shfl_xor(part, 8);
  part += __shfl_xor(part, 16); part += __shfl_xor(part, 32);
  if (lane == 0) atomicAdd(lsum, part);
  if (lane < 16) {
    scodes[(long)bh * LL + rbase + lane] = (float)widx;
    finalIdx[wave * 16 + lane] = widx;
  }
  __syncthreads();
  {
    int r = tid >> 2, p = (tid & 3) * 16;
    int code = finalIdx[r];
    const unsigned short* src = cbb + ((long)h * NC + code) * HDD + p;
    unsigned short* dst = khat + ((long)bh * LL + rb * 64 + r) * HDD + p;
    *(u16x8*)(dst)     = *(const u16x8*)(src);
    *(u16x8*)(dst + 8) = *(const u16x8*)(src + 8);
  }
}

// ---------------- flash attention: paired q-tiles, cooperative LDS-staged K/V ----------------
// m97-style 2-barrier K-loop. FIX from round 9: each staging thread writes TWO
// 16B chunks per row (sc and sc+32) -> full 64-short rows (was half-filled LDS -> NaN).
__global__ __launch_bounds__(256) void attn_kernel(
    const unsigned short* __restrict__ qb, const unsigned short* __restrict__ khat,
    const unsigned short* __restrict__ vt, unsigned short* __restrict__ attnb) {
  __shared__ __align__(16) unsigned short Pbuf[4][2][16 * 72];  // 18432 B
  __shared__ __align__(16) unsigned short Kbuf[64 * 72];        // 9216 B (pad 72: frag reads 2-way)
  __shared__ __align__(16) unsigned short Vbuf[64 * 72];        // 9216 B
  int tid = threadIdx.x, wave = tid >> 6, lane = tid & 63;
  int quad = lane >> 4, col = lane & 15;
  int pi = blockIdx.x;          // 0..15: pairs q-tile pi with 31-pi
  int bh = blockIdx.y;
  int b = bh >> 4, h = bh & 15;
  int ta = pi, tb = 31 - pi;    // ta < tb always
  int qbA = ta * 64 + wave * 16;
  int qbB = tb * 64 + wave * 16;
  const unsigned short* qrA = qb + ((long)bh * LL + qbA + col) * HDD;
  const unsigned short* qrB = qb + ((long)bh * LL + qbB + col) * HDD;
  bf16x8 aqA0 = *(const bf16x8*)(qrA + quad * 8);
  bf16x8 aqA1 = *(const bf16x8*)(qrA + 32 + quad * 8);
  bf16x8 aqB0 = *(const bf16x8*)(qrB + quad * 8);
  bf16x8 aqB1 = *(const bf16x8*)(qrB + 32 + quad * 8);
  float lA[4] = {0.f, 0.f, 0.f, 0.f}, lB[4] = {0.f, 0.f, 0.f, 0.f};
  f32x4 oA[4] = {}, oB[4] = {};
  unsigned short* PA = Pbuf[wave][0];
  unsigned short* PB = Pbuf[wave][1];
  const unsigned short* kh = khat + (long)bh * LL * HDD;
  const unsigned short* vh = vt + (long)bh * HDD * LL;
  // staging role: thread t covers row=t>>2 (0..63), chunks sc and sc+32
  int srow = tid >> 2, sc = (tid & 3) * 8;
  const unsigned short* gK = kh + (long)srow * HDD + sc;
  const unsigned short* gV = vh + (long)srow * LL + sc;
  unsigned short* lK = Kbuf + srow * 72 + sc;
  unsigned short* lV = Vbuf + srow * 72 + sc;
  const float SCL = 0.18033688011112042f;  // log2(e) / 8
  for (int kt = 0; kt <= tb; kt++) {
    int kbase = kt * 64;
    bool actA = (kt <= ta);
    __syncthreads();
    {
      const unsigned short* srcK = gK + (long)kbase * HDD;
      const unsigned short* srcV = gV + kbase;
      *(u16x8*)lK        = *(const u16x8*)(srcK);
      *(u16x8*)(lK + 32) = *(const u16x8*)(srcK + 32);
      *(u16x8*)lV        = *(const u16x8*)(srcV);
      *(u16x8*)(lV + 32) = *(const u16x8*)(srcV + 32);
    }
    __syncthreads();
    f32x4 zA[4], zB[4];
    for (int nt = 0; nt < 4; nt++) {
      const unsigned short* krow = Kbuf + (nt * 16 + col) * 72;
      bf16x8 k0 = *(const bf16x8*)(krow + quad * 8);
      bf16x8 k1 = *(const bf16x8*)(krow + 32 + quad * 8);
      f32x4 z = {};
      z = __builtin_amdgcn_mfma_f32_16x16x32_bf16(aqB0, k0, z, 0, 0, 0);
      z = __builtin_amdgcn_mfma_f32_16x16x32_bf16(aqB1, k1, z, 0, 0, 0);
      zB[nt] = z;
      if (actA) {
        f32x4 y = {};
        y = __builtin_amdgcn_mfma_f32_16x16x32_bf16(aqA0, k0, y, 0, 0, 0);
        y = __builtin_amdgcn_mfma_f32_16x16x32_bf16(aqA1, k1, y, 0, 0, 0);
        zA[nt] = y;
      }
    }
    for (int nt = 0; nt < 4; nt++) {
      int key = kbase + nt * 16 + col;
      for (int r = 0; r < 4; r++) {
        float sc2 = zB[nt][r] * SCL;
        if (kt == tb && key > qbB + quad * 4 + r) sc2 = -1e30f;
        float p = exp2f(sc2);
        lB[r] += p;
        PB[(quad * 4 + r) * 72 + nt * 16 + col] = __builtin_bit_cast(unsigned short, (__bf16)p);
      }
    }
    if (actA) {
      for (int nt = 0; nt < 4; nt++) {
        int key = kbase + nt * 16 + col;
        for (int r = 0; r < 4; r++) {
          float sc2 = zA[nt][r] * SCL;
          if (kt == ta && key > qbA + quad * 4 + r) sc2 = -1e30f;
          float p = exp2f(sc2);
          lA[r] += p;
          PA[(quad * 4 + r) * 72 + nt * 16 + col] = __builtin_bit_cast(unsigned short, (__bf16)p);
        }
      }
    }
    bf16x8 apB0 = *(const bf16x8*)(PB + col * 72 + quad * 8);
    bf16x8 apB1 = *(const bf16x8*)(PB + col * 72 + 32 + quad * 8);
    bf16x8 apA0, apA1;
    if (actA) {
      apA0 = *(const bf16x8*)(PA + col * 72 + quad * 8);
      apA1 = *(const bf16x8*)(PA + col * 72 + 32 + quad * 8);
    }
    for (int nt = 0; nt < 4; nt++) {
      const unsigned short* vrow = Vbuf + (nt * 16 + col) * 72;
      bf16x8 v0 = *(const bf16x8*)(vrow + quad * 8);
      bf16x8 v1 = *(const bf16x8*)(vrow + 32 + quad * 8);
      oB[nt] = __builtin_amdgcn_mfma_f32_16x16x32_bf16(apB0, v0, oB[nt], 0, 0, 0);
      oB[nt] = __builtin_amdgcn_mfma_f32_16x16x32_bf16(apB1, v1, oB[nt], 0, 0, 0);
      if (actA) {
        oA[nt] = __builtin_amdgcn_mfma_f32_16x16x32_bf16(apA0, v0, oA[nt], 0, 0, 0);
        oA[nt] = __builtin_amdgcn_mfma_f32_16x16x32_bf16(apA1, v1, oA[nt], 0, 0, 0);
      }
    }
  }
  float invA[4], invB[4];
  for (int r = 0; r < 4; r++) {
    float t = lA[r];
    t += __shfl_xor(t, 1); t += __shfl_xor(t, 2);
    t += __shfl_xor(t, 4); t += __shfl_xor(t, 8);
    invA[r] = 1.0f / t;
    float u = lB[r];
    u += __shfl_xor(u, 1); u += __shfl_xor(u, 2);
    u += __shfl_xor(u, 4); u += __shfl_xor(u, 8);
    invB[r] = 1.0f / u;
  }
  for (int r = 0; r < 4; r++) {
    int rowA = qbA + quad * 4 + r;
    int rowB = qbB + quad * 4 + r;
    for (int nt = 0; nt < 4; nt++) {
      int hd = nt * 16 + col;
      attnb[((long)b * LL + rowA) * DD + h * HDD + hd] = f2bf(oA[nt][r] * invA[r]);
      attnb[((long)b * LL + rowB) * DD + h * HDD + hd] = f2bf(oB[nt][r] * invB[r]);
    }
  }
}

// ---------------- GEMM2: out = attn * Wo^T (fp32 store) ----------------
__global__ __launch_bounds__(256) void gemm_out(
    const unsigned short* __restrict__ attnb, const unsigned short* __restrict__ wob,
    float* __restrict__ out) {
  __shared__ __align__(16) unsigned short As[128 * 32];
  __shared__ __align__(16) unsigned short Bs[128 * 32];
  int tid = threadIdx.x;
  int wave = tid >> 6, lane = tid & 63;
  int quad = lane >> 4, col = lane & 15;
  int m0 = blockIdx.y * 128;
  int n0 = blockIdx.x * 128;
  f32x4 acc[4][4] = {};
  int row_in = (wave << 4) + (lane >> 2);
  int seg = lane & 3;
  const unsigned short* gA0 = attnb + (long)(m0 + row_in) * DD + seg * 8;
  const unsigned short* gA1 = attnb + (long)(m0 + 64 + row_in) * DD + seg * 8;
  const unsigned short* gB0 = wob + (long)(n0 + row_in) * DD + seg * 8;
  const unsigned short* gB1 = wob + (long)(n0 + 64 + row_in) * DD + seg * 8;
  unsigned short* lA0 = As + wave * 512;
  unsigned short* lA1 = As + 2048 + wave * 512;
  unsigned short* lB0 = Bs + wave * 512;
  unsigned short* lB1 = Bs + 2048 + wave * 512;
  int wm = wave & 1, wn = wave >> 1;
  const unsigned short* pa = As + (wm * 64 + col) * 32 + quad * 8;
  const unsigned short* pb = Bs + (wn * 64 + col) * 32 + quad * 8;
  for (int kk = 0; kk < DD; kk += 32) {
    __syncthreads();
    load_lds16(gA0 + kk, lA0);
    load_lds16(gA1 + kk, lA1);
    load_lds16(gB0 + kk, lB0);
    load_lds16(gB1 + kk, lB1);
    __syncthreads();
    bf16x8 af[4], bfr[4];
    for (int t = 0; t < 4; t++) af[t]  = *(const bf16x8*)(pa + t * 512);
    for (int t = 0; t < 4; t++) bfr[t] = *(const bf16x8*)(pb + t * 512);
    for (int mt = 0; mt < 4; mt++)
      for (int nt = 0; nt < 4; nt++)
        acc[mt][nt] = __builtin_amdgcn_mfma_f32_16x16x32_bf16(af[mt], bfr[nt], acc[mt][nt], 0, 0, 0);
  }
  for (int mt = 0; mt < 4; mt++)
    for (int nt = 0; nt < 4; nt++) {
      int mbase = m0 + wm * 64 + mt * 16 + quad * 4;
      int n = n0 + wn * 64 + nt * 16 + col;
      for (int r = 0; r < 4; r++)
        out[(long)(mbase + r) * DD + n] = acc[mt][nt][r];
    }
}

// ---------------- finalize scalars ----------------
__global__ void finalize(const float* __restrict__ lsum, float* __restrict__ out) {
  if (threadIdx.x == 0) {
    float v = lsum[0] / (float)(BB * HH * LL);
    out[4194304] = v;
    out[4194305] = v;
  }
}

extern "C" void kernel_launch(void* const* d_in, const int* in_sizes, int n_in,
                              void* d_out, int out_size, void* d_ws, size_t ws_size,
                              hipStream_t stream) {
  const float* x  = (const float*)d_in[0];
  const float* wq = (const float*)d_in[1];
  const float* wk = (const float*)d_in[2];
  const float* wv = (const float*)d_in[3];
  const float* wo = (const float*)d_in[4];
  const float* cb = (const float*)d_in[5];
  float* out = (float*)d_out;

  char* ws = (char*)d_ws;
  size_t off = 0;
  auto alloc = [&](size_t bytes) {
    void* p = ws + off;
    off = (off + bytes + 255) & ~(size_t)255;
    return p;
  };
  unsigned short* xb    = (unsigned short*)alloc(4194304 * 2);
  unsigned short* wb    = (unsigned short*)alloc(3145728 * 2);
  unsigned short* wob   = (unsigned short*)alloc(1048576 * 2);
  unsigned short* cbb   = (unsigned short*)alloc(524288 * 2);
  unsigned short* cbl   = (unsigned short*)alloc(524288 * 2);
  unsigned short* qb    = (unsigned short*)alloc(4194304 * 2);
  unsigned short* vt    = (unsigned short*)alloc(4194304 * 2);
  unsigned short* khat  = (unsigned short*)alloc(4194304 * 2);
  unsigned short* attnb = (unsigned short*)alloc(4194304 * 2);
  float* kf   = (float*)alloc(4194304 * 4);
  float* c2   = (float*)alloc(8192 * 4);
  float* lsum = (float*)alloc(256);

  cast_all<<<dim3(4096), dim3(256), 0, stream>>>(x, wq, wk, wv, wo, cb, xb, wb, wob, cbb, cbl, lsum);
  c2_kernel<<<dim3(32), dim3(256), 0, stream>>>(cb, c2);
  gemm_qv<<<dim3(16, 32), dim3(256), 0, stream>>>(xb, wb, qb, vt);
  kgemm_f32<<<dim3(16, 32), dim3(256), 0, stream>>>(x, wk, kf);
  vq_mfma<<<dim3(32, 32), dim3(256), 0, stream>>>(kf, cb, c2, cbb, cbl, khat, out + 4194306, lsum);
  attn_kernel<<<dim3(16, 32), dim3(256), 0, stream>>>(qb, khat, vt, attnb);
  gemm_out<<<dim3(8, 32), dim3(256), 0, stream>>>(attnb, wob, out);
  finalize<<<dim3(1), dim3(64), 0, stream>>>(lsum, out);
}